// Round 3
// baseline (235.716 us; speedup 1.0000x reference)
//
#include <hip/hip_runtime.h>

#define HH 256
#define WW 256
#define NB 4
#define NC 128
#define HW (HH * WW)

// ---------- bf16 helpers (manual, RNE) ----------
__device__ __forceinline__ float blo(unsigned int u) { return __uint_as_float(u << 16); }
__device__ __forceinline__ float bhi(unsigned int u) { return __uint_as_float(u & 0xffff0000u); }
__device__ __forceinline__ unsigned int bf16_rne(float f) {
    unsigned int u = __float_as_uint(f);
    return (u + 0x7fffu + ((u >> 16) & 1u)) >> 16;  // finite inputs only
}
__device__ __forceinline__ unsigned int pack_bf16(float a, float b) {
    return bf16_rne(a) | (bf16_rne(b) << 16);
}
union U4 { uint4 v; unsigned int w[4]; };

// =====================================================================
// prep2: CHW f32 -> HWC bf16 at scales 0/1/2, fused, no LDS.
// Lane owns 2 adjacent pixels (float2 per channel, coalesced).
// 8-lane group = 4x4 pixel tile:  l8 = ly*2+lx, lane covers
// row (by*4+ly), cols (bx*128 + tt*4 + 2*lx) + {0,1}.
// scale1 (2x2 avg): in-lane pair sum + shfl_xor(2)   [DPP, cheap]
// scale2 (middle 2x2 of 4x4): pick col + shfl_xor(1) + shfl_xor(6)
// =====================================================================
__global__ __launch_bounds__(256) void prep2_kernel(
        const float* __restrict__ feat1, const float* __restrict__ feat2,
        unsigned int* __restrict__ s0f1, unsigned int* __restrict__ s0f2,
        unsigned int* __restrict__ d1f1, unsigned int* __restrict__ d1f2,
        unsigned int* __restrict__ d2f1, unsigned int* __restrict__ d2f2) {
    int z = blockIdx.z;
    int b = z & 3;
    const float* fp = (z < 4 ? feat1 : feat2) + (size_t)b * NC * HW;
    unsigned int* s0 = (z < 4 ? s0f1 : s0f2);
    unsigned int* d1 = (z < 4 ? d1f1 : d1f2);
    unsigned int* d2 = (z < 4 ? d2f1 : d2f2);

    int tid = threadIdx.x;
    int tt = tid >> 3;   // 4x4 tile index within block: 0..31
    int l8 = tid & 7;
    int lx = l8 & 1;     // lane col-pair within tile (covers px 2*lx, 2*lx+1)
    int ly = l8 >> 1;    // row within tile: 0..3
    int bx = blockIdx.x; // 0..1  (128 cols each)
    int by = blockIdx.y; // 0..63 (4 rows each)

    int y  = by * 4 + ly;
    int xA = bx * 128 + tt * 4 + lx * 2;
    const float* src = fp + (size_t)y * WW + xA;

    size_t p0A = ((size_t)(b * HH + y) * WW + xA) * 64;  // uint index of pixel vec
    size_t p0B = p0A + 64;
    int y1 = by * 2 + (ly >> 1);
    int x1 = bx * 64 + tt * 2 + lx;
    size_t p1 = ((size_t)(b * 128 + y1) * 128 + x1) * 64;
    int y2 = by;
    int x2 = bx * 32 + tt;
    size_t p2 = ((size_t)(b * 64 + y2) * 64 + x2) * 64;

    bool w1 = ((ly & 1) == 0);  // scale1 representative lanes
    bool w2 = (l8 == 2);        // scale2 representative lane of the coset {2,3,4,5}

    U4 bA, bB, b1, b2;
#pragma unroll 8
    for (int cp = 0; cp < 64; ++cp) {
        float2 v0 = *(const float2*)(src + (size_t)(2 * cp) * HW);
        float2 v1 = *(const float2*)(src + (size_t)(2 * cp + 1) * HW);
        int j = cp & 3;
        bA.w[j] = pack_bf16(v0.x, v1.x);
        bB.w[j] = pack_bf16(v0.y, v1.y);

        // scale1: aligned 2x2 quad = this lane's pair + row-neighbor (ly^1)
        float pq0 = v0.x + v0.y;
        float pq1 = v1.x + v1.y;
        float q0 = pq0 + __shfl_xor(pq0, 2);
        float q1 = pq1 + __shfl_xor(pq1, 2);
        b1.w[j] = pack_bf16(0.25f * q0, 0.25f * q1);

        // scale2: avg of tile pixels (rows 1..2, cols 1..2)
        float m0 = lx ? v0.x : v0.y;  // lane's middle-column value
        float m1 = lx ? v1.x : v1.y;
        float s0v = m0 + __shfl_xor(m0, 1);
        float s1v = m1 + __shfl_xor(m1, 1);
        s0v += __shfl_xor(s0v, 6);
        s1v += __shfl_xor(s1v, 6);
        b2.w[j] = pack_bf16(0.25f * s0v, 0.25f * s1v);

        if (j == 3) {
            int ci = cp - 3;
            *(uint4*)(s0 + p0A + ci) = bA.v;
            *(uint4*)(s0 + p0B + ci) = bB.v;
            if (w1) *(uint4*)(d1 + p1 + ci) = b1.v;
            if (w2) *(uint4*)(d2 + p2 + ci) = b2.v;
        }
    }
}

// =====================================================================
// HWC corr: 16 lanes per pixel, one uint4 (8 bf16 ch) per lane.
// All 5 reads (f1 + 4 corners) are contiguous 256B per pixel.
// =====================================================================
template <int SCALE>
__global__ void corr_hwc(const unsigned int* __restrict__ f1,
                         const unsigned int* __restrict__ f2,
                         const float* __restrict__ offs,
                         float* __restrict__ out) {
    constexpr int S = (SCALE == 0) ? 256 : (SCALE == 1 ? 128 : 64);
    constexpr int LOGS = (SCALE == 0) ? 8 : (SCALE == 1 ? 7 : 6);
    int tid = threadIdx.x;
    int lane = tid & 15;
    int pix = blockIdx.x * 16 + (tid >> 4);
    int b = pix >> (2 * LOGS);
    int p = pix & (S * S - 1);
    int y = p >> LOGS;
    int x = p & (S - 1);

    const float* offx = offs + ((size_t)b * 6 + 2 * SCALE) * (HH * WW);
    const float* offy = offx + HH * WW;
    float dx, dy;
    if constexpr (SCALE == 0) {
        dx = offx[y * WW + x];
        dy = offy[y * WW + x];
    } else if constexpr (SCALE == 1) {
        const float* px = offx + (2 * y) * WW + 2 * x;
        const float* py = offy + (2 * y) * WW + 2 * x;
        dx = 0.125f * (px[0] + px[1] + px[WW] + px[WW + 1]);
        dy = 0.125f * (py[0] + py[1] + py[WW] + py[WW + 1]);
    } else {
        const float* px = offx + (4 * y + 1) * WW + 4 * x + 1;
        const float* py = offy + (4 * y + 1) * WW + 4 * x + 1;
        dx = 0.0625f * (px[0] + px[1] + px[WW] + px[WW + 1]);
        dy = 0.0625f * (py[0] + py[1] + py[WW] + py[WW + 1]);
    }

    float sx = (float)x + dx;
    float sy = (float)y + dy;
    float x0f = floorf(sx), y0f = floorf(sy);
    float wx1 = sx - x0f, wy1 = sy - y0f;
    float wx0 = 1.0f - wx1, wy0 = 1.0f - wy1;
    int x0 = (int)x0f, y0 = (int)y0f;
    int x1 = x0 + 1, y1 = y0 + 1;
    bool vx0 = (x0 >= 0) & (x0 < S);
    bool vx1 = (x1 >= 0) & (x1 < S);
    bool vy0 = (y0 >= 0) & (y0 < S);
    bool vy1 = (y1 >= 0) & (y1 < S);
    float w00 = wy0 * wx0 * (float)(vy0 & vx0);
    float w01 = wy0 * wx1 * (float)(vy0 & vx1);
    float w10 = wy1 * wx0 * (float)(vy1 & vx0);
    float w11 = wy1 * wx1 * (float)(vy1 & vx1);
    int cx0 = min(max(x0, 0), S - 1), cx1 = min(max(x1, 0), S - 1);
    int cy0 = min(max(y0, 0), S - 1), cy1 = min(max(y1, 0), S - 1);
    size_t pb = (size_t)b << (2 * LOGS);
    size_t i00 = pb + (cy0 << LOGS) + cx0, i01 = pb + (cy0 << LOGS) + cx1;
    size_t i10 = pb + (cy1 << LOGS) + cx0, i11 = pb + (cy1 << LOGS) + cx1;

    int lo = lane * 4;
    U4 a, c00, c01, c10, c11;
    a.v   = *(const uint4*)(f1 + ((size_t)pix << 6) + lo);
    c00.v = *(const uint4*)(f2 + (i00 << 6) + lo);
    c01.v = *(const uint4*)(f2 + (i01 << 6) + lo);
    c10.v = *(const uint4*)(f2 + (i10 << 6) + lo);
    c11.v = *(const uint4*)(f2 + (i11 << 6) + lo);

    float acc = 0.0f;
#pragma unroll
    for (int j = 0; j < 4; ++j) {
        float s_lo = w00 * blo(c00.w[j]) + w01 * blo(c01.w[j]) + w10 * blo(c10.w[j]) + w11 * blo(c11.w[j]);
        float s_hi = w00 * bhi(c00.w[j]) + w01 * bhi(c01.w[j]) + w10 * bhi(c10.w[j]) + w11 * bhi(c11.w[j]);
        acc = fmaf(blo(a.w[j]), s_lo, acc);
        acc = fmaf(bhi(a.w[j]), s_hi, acc);
    }
    acc += __shfl_xor(acc, 8);
    acc += __shfl_xor(acc, 4);
    acc += __shfl_xor(acc, 2);
    acc += __shfl_xor(acc, 1);

    if (lane == 0) {
        if constexpr (SCALE == 0) {
            out[((size_t)b * 3) * (HH * WW) + p] = acc;
        } else {
            out[(size_t)b * (S * S) + p] = acc;
        }
    }
}

// ---------------- upsample corr back to 256x256 ----------------
template <int SCALE>
__global__ void up_kernel(const float* __restrict__ corr, float* __restrict__ out) {
    constexpr int S = (SCALE == 1) ? 128 : 64;
    constexpr float R = (float)S / 256.0f;
    int idx = blockIdx.x * blockDim.x + threadIdx.x;
    if (idx >= NB * HH * WW) return;
    int x = idx & 255;
    int t = idx >> 8;
    int y = t & 255;
    int b = t >> 8;
    float srcx = fminf(fmaxf(((float)x + 0.5f) * R - 0.5f, 0.0f), (float)(S - 1));
    float srcy = fminf(fmaxf(((float)y + 0.5f) * R - 0.5f, 0.0f), (float)(S - 1));
    int x0 = (int)srcx;
    int y0 = (int)srcy;
    int x1 = min(x0 + 1, S - 1), y1 = min(y0 + 1, S - 1);
    float wx = srcx - (float)x0, wy = srcy - (float)y0;
    const float* cp = corr + (size_t)b * (S * S);
    float v0 = cp[y0 * S + x0] * (1.0f - wx) + cp[y0 * S + x1] * wx;
    float v1 = cp[y1 * S + x0] * (1.0f - wx) + cp[y1 * S + x1] * wx;
    out[((size_t)b * 3 + SCALE) * (HH * WW) + y * WW + x] = (1.0f - wy) * v0 + wy * v1;
}

extern "C" void kernel_launch(void* const* d_in, const int* in_sizes, int n_in,
                              void* d_out, int out_size, void* d_ws, size_t ws_size,
                              hipStream_t stream) {
    const float* feat1 = (const float*)d_in[0];
    const float* feat2 = (const float*)d_in[1];
    const float* offs  = (const float*)d_in[2];
    float* out = (float*)d_out;

    const size_t n_s0 = (size_t)NB * HH * WW * 64;
    const size_t n_d1 = (size_t)NB * 128 * 128 * 64;
    const size_t n_d2 = (size_t)NB * 64 * 64 * 64;
    const size_t n_c1 = (size_t)NB * 128 * 128;
    const size_t n_c2 = (size_t)NB * 64 * 64;
    const size_t need = (2 * (n_s0 + n_d1 + n_d2) + n_c1 + n_c2) * 4;
    if (ws_size < need) return;

    unsigned int* ws = (unsigned int*)d_ws;
    unsigned int* s0f1 = ws;
    unsigned int* s0f2 = s0f1 + n_s0;
    unsigned int* d1f1 = s0f2 + n_s0;
    unsigned int* d1f2 = d1f1 + n_d1;
    unsigned int* d2f1 = d1f2 + n_d1;
    unsigned int* d2f2 = d2f1 + n_d2;
    float* corr1 = (float*)(d2f2 + n_d2);
    float* corr2 = corr1 + n_c1;

    prep2_kernel<<<dim3(2, 64, 8), 256, 0, stream>>>(feat1, feat2, s0f1, s0f2,
                                                     d1f1, d1f2, d2f1, d2f2);

    corr_hwc<0><<<NB * 65536 / 16, 256, 0, stream>>>(s0f1, s0f2, offs, out);
    corr_hwc<1><<<NB * 16384 / 16, 256, 0, stream>>>(d1f1, d1f2, offs, corr1);
    corr_hwc<2><<<NB * 4096 / 16, 256, 0, stream>>>(d2f1, d2f2, offs, corr2);

    up_kernel<1><<<(NB * HH * WW + 255) / 256, 256, 0, stream>>>(corr1, out);
    up_kernel<2><<<(NB * HH * WW + 255) / 256, 256, 0, stream>>>(corr2, out);
}

// Round 4
// 159.599 us; speedup vs baseline: 1.4769x; 1.4769x over previous
//
#include <hip/hip_runtime.h>

#define HH 256
#define WW 256
#define NB 4
#define NC 128
#define HW (HH * WW)

// swizzled LDS address: pixel p (0..63), channel c (0..127).
// even XOR keeps channel-pair adjacency + 8B alignment for b64 reads.
#define LADDR(p, c) (((p) << 7) + ((c) ^ ((((p) & 15)) << 1)))

// ---------- bf16 helpers (manual, RNE) ----------
__device__ __forceinline__ float blo(unsigned int u) { return __uint_as_float(u << 16); }
__device__ __forceinline__ float bhi(unsigned int u) { return __uint_as_float(u & 0xffff0000u); }
__device__ __forceinline__ unsigned int bf16_rne(float f) {
    unsigned int u = __float_as_uint(f);
    return (u + 0x7fffu + ((u >> 16) & 1u)) >> 16;  // finite inputs only
}
__device__ __forceinline__ unsigned int pack_bf16(float a, float b) {
    return bf16_rne(a) | (bf16_rne(b) << 16);
}
union U4 { uint4 v; unsigned int w[4]; };

// =====================================================================
// prep3: CHW f32 -> HWC bf16 (scales 0/1/2) via swizzled 32KB f32 LDS tile.
// Tile: 4 rows x 16 cols x 128 ch. Loads float4/lane; stores uint4/lane,
// 1KB-contiguous per wave. d1/d2 averaged in f32 from the same tile.
// =====================================================================
__global__ __launch_bounds__(256) void prep3_kernel(
        const float* __restrict__ feat1, const float* __restrict__ feat2,
        unsigned int* __restrict__ s0f1, unsigned int* __restrict__ s0f2,
        unsigned int* __restrict__ d1f1, unsigned int* __restrict__ d1f2,
        unsigned int* __restrict__ d2f1, unsigned int* __restrict__ d2f2) {
    __shared__ float lds[64 * 128];

    int z = blockIdx.z;
    int b = z & 3;
    const float* src = (z < 4 ? feat1 : feat2) + (size_t)b * NC * HW;
    unsigned int* s0 = (z < 4 ? s0f1 : s0f2);
    unsigned int* d1 = (z < 4 ? d1f1 : d1f2);
    unsigned int* d2 = (z < 4 ? d2f1 : d2f2);

    int tid = threadIdx.x;
    int bx = blockIdx.x;   // 0..15 : 16-col tiles
    int by = blockIdx.y;   // 0..63 : 4-row tiles
    int x0 = bx * 16, y0 = by * 4;

    // ---- load phase: lane = (channel band, float4 pos); 8 iters ----
    {
        int cband = tid >> 4;        // 0..15
        int f4 = tid & 15;
        int py = f4 >> 2, px4 = f4 & 3;
        const float* lp = src + (size_t)(y0 + py) * WW + x0 + px4 * 4;
        int pbase = py * 16 + px4 * 4;
#pragma unroll
        for (int it = 0; it < 8; ++it) {
            int c = it * 16 + cband;
            float4 v = *(const float4*)(lp + (size_t)c * HW);
            lds[LADDR(pbase + 0, c)] = v.x;
            lds[LADDR(pbase + 1, c)] = v.y;
            lds[LADDR(pbase + 2, c)] = v.z;
            lds[LADDR(pbase + 3, c)] = v.w;
        }
    }
    __syncthreads();

    int c8 = tid & 15;   // channel-group (8 ch = 16B) within pixel vector

    // ---- s0 store: 4 iters, wave stores 1KB contiguous ----
    {
        int pq = tid >> 4;   // 0..15 : pixel col within row
#pragma unroll
        for (int it = 0; it < 4; ++it) {
            int p = it * 16 + pq;           // row=it, col=pq
            U4 u;
#pragma unroll
            for (int j = 0; j < 4; ++j) {
                float2 v = *(const float2*)&lds[LADDR(p, c8 * 8 + 2 * j)];
                u.w[j] = pack_bf16(v.x, v.y);
            }
            size_t pix = ((size_t)(b * HH + y0 + it) * WW + (x0 + pq));
            *(uint4*)(s0 + pix * 64 + c8 * 4) = u.v;
        }
    }

    // ---- d1: 2x8 pixels, f32 quad average ----
    {
        int dp = tid >> 4;          // 0..15
        int qy = dp >> 3, qx = dp & 7;
        int p00 = (2 * qy) * 16 + 2 * qx;
        U4 u;
#pragma unroll
        for (int j = 0; j < 4; ++j) {
            int ch = c8 * 8 + 2 * j;
            float2 a0 = *(const float2*)&lds[LADDR(p00,      ch)];
            float2 a1 = *(const float2*)&lds[LADDR(p00 + 1,  ch)];
            float2 a2 = *(const float2*)&lds[LADDR(p00 + 16, ch)];
            float2 a3 = *(const float2*)&lds[LADDR(p00 + 17, ch)];
            u.w[j] = pack_bf16(0.25f * (a0.x + a1.x + a2.x + a3.x),
                               0.25f * (a0.y + a1.y + a2.y + a3.y));
        }
        size_t pix = ((size_t)(b * 128 + by * 2 + qy) * 128 + (bx * 8 + qx));
        *(uint4*)(d1 + pix * 64 + c8 * 4) = u.v;
    }

    // ---- d2: 1x4 pixels (rows 1..2, cols 4k+1..4k+2) ----
    if (tid < 64) {
        int dp = tid >> 4;          // 0..3
        int p00 = 16 + 4 * dp + 1;
        U4 u;
#pragma unroll
        for (int j = 0; j < 4; ++j) {
            int ch = c8 * 8 + 2 * j;
            float2 a0 = *(const float2*)&lds[LADDR(p00,      ch)];
            float2 a1 = *(const float2*)&lds[LADDR(p00 + 1,  ch)];
            float2 a2 = *(const float2*)&lds[LADDR(p00 + 16, ch)];
            float2 a3 = *(const float2*)&lds[LADDR(p00 + 17, ch)];
            u.w[j] = pack_bf16(0.25f * (a0.x + a1.x + a2.x + a3.x),
                               0.25f * (a0.y + a1.y + a2.y + a3.y));
        }
        size_t pix = ((size_t)(b * 64 + by) * 64 + (bx * 4 + dp));
        *(uint4*)(d2 + pix * 64 + c8 * 4) = u.v;
    }
}

// =====================================================================
// HWC corr: 16 lanes per pixel, one uint4 (8 bf16 ch) per lane.
// =====================================================================
template <int SCALE>
__global__ void corr_hwc(const unsigned int* __restrict__ f1,
                         const unsigned int* __restrict__ f2,
                         const float* __restrict__ offs,
                         float* __restrict__ out) {
    constexpr int S = (SCALE == 0) ? 256 : (SCALE == 1 ? 128 : 64);
    constexpr int LOGS = (SCALE == 0) ? 8 : (SCALE == 1 ? 7 : 6);
    int tid = threadIdx.x;
    int lane = tid & 15;
    int pix = blockIdx.x * 16 + (tid >> 4);
    int b = pix >> (2 * LOGS);
    int p = pix & (S * S - 1);
    int y = p >> LOGS;
    int x = p & (S - 1);

    const float* offx = offs + ((size_t)b * 6 + 2 * SCALE) * (HH * WW);
    const float* offy = offx + HH * WW;
    float dx, dy;
    if constexpr (SCALE == 0) {
        dx = offx[y * WW + x];
        dy = offy[y * WW + x];
    } else if constexpr (SCALE == 1) {
        const float* px = offx + (2 * y) * WW + 2 * x;
        const float* py = offy + (2 * y) * WW + 2 * x;
        dx = 0.125f * (px[0] + px[1] + px[WW] + px[WW + 1]);
        dy = 0.125f * (py[0] + py[1] + py[WW] + py[WW + 1]);
    } else {
        const float* px = offx + (4 * y + 1) * WW + 4 * x + 1;
        const float* py = offy + (4 * y + 1) * WW + 4 * x + 1;
        dx = 0.0625f * (px[0] + px[1] + px[WW] + px[WW + 1]);
        dy = 0.0625f * (py[0] + py[1] + py[WW] + py[WW + 1]);
    }

    float sx = (float)x + dx;
    float sy = (float)y + dy;
    float x0f = floorf(sx), y0f = floorf(sy);
    float wx1 = sx - x0f, wy1 = sy - y0f;
    float wx0 = 1.0f - wx1, wy0 = 1.0f - wy1;
    int x0 = (int)x0f, y0 = (int)y0f;
    int x1 = x0 + 1, y1 = y0 + 1;
    bool vx0 = (x0 >= 0) & (x0 < S);
    bool vx1 = (x1 >= 0) & (x1 < S);
    bool vy0 = (y0 >= 0) & (y0 < S);
    bool vy1 = (y1 >= 0) & (y1 < S);
    float w00 = wy0 * wx0 * (float)(vy0 & vx0);
    float w01 = wy0 * wx1 * (float)(vy0 & vx1);
    float w10 = wy1 * wx0 * (float)(vy1 & vx0);
    float w11 = wy1 * wx1 * (float)(vy1 & vx1);
    int cx0 = min(max(x0, 0), S - 1), cx1 = min(max(x1, 0), S - 1);
    int cy0 = min(max(y0, 0), S - 1), cy1 = min(max(y1, 0), S - 1);
    size_t pb = (size_t)b << (2 * LOGS);
    size_t i00 = pb + (cy0 << LOGS) + cx0, i01 = pb + (cy0 << LOGS) + cx1;
    size_t i10 = pb + (cy1 << LOGS) + cx0, i11 = pb + (cy1 << LOGS) + cx1;

    int lo = lane * 4;
    U4 a, c00, c01, c10, c11;
    a.v   = *(const uint4*)(f1 + ((size_t)pix << 6) + lo);
    c00.v = *(const uint4*)(f2 + (i00 << 6) + lo);
    c01.v = *(const uint4*)(f2 + (i01 << 6) + lo);
    c10.v = *(const uint4*)(f2 + (i10 << 6) + lo);
    c11.v = *(const uint4*)(f2 + (i11 << 6) + lo);

    float acc = 0.0f;
#pragma unroll
    for (int j = 0; j < 4; ++j) {
        float s_lo = w00 * blo(c00.w[j]) + w01 * blo(c01.w[j]) + w10 * blo(c10.w[j]) + w11 * blo(c11.w[j]);
        float s_hi = w00 * bhi(c00.w[j]) + w01 * bhi(c01.w[j]) + w10 * bhi(c10.w[j]) + w11 * bhi(c11.w[j]);
        acc = fmaf(blo(a.w[j]), s_lo, acc);
        acc = fmaf(bhi(a.w[j]), s_hi, acc);
    }
    acc += __shfl_xor(acc, 8);
    acc += __shfl_xor(acc, 4);
    acc += __shfl_xor(acc, 2);
    acc += __shfl_xor(acc, 1);

    if (lane == 0) {
        if constexpr (SCALE == 0) {
            out[((size_t)b * 3) * (HH * WW) + p] = acc;
        } else {
            out[(size_t)b * (S * S) + p] = acc;
        }
    }
}

// ---------------- upsample corr back to 256x256 ----------------
template <int SCALE>
__global__ void up_kernel(const float* __restrict__ corr, float* __restrict__ out) {
    constexpr int S = (SCALE == 1) ? 128 : 64;
    constexpr float R = (float)S / 256.0f;
    int idx = blockIdx.x * blockDim.x + threadIdx.x;
    if (idx >= NB * HH * WW) return;
    int x = idx & 255;
    int t = idx >> 8;
    int y = t & 255;
    int b = t >> 8;
    float srcx = fminf(fmaxf(((float)x + 0.5f) * R - 0.5f, 0.0f), (float)(S - 1));
    float srcy = fminf(fmaxf(((float)y + 0.5f) * R - 0.5f, 0.0f), (float)(S - 1));
    int x0 = (int)srcx;
    int y0 = (int)srcy;
    int x1 = min(x0 + 1, S - 1), y1 = min(y0 + 1, S - 1);
    float wx = srcx - (float)x0, wy = srcy - (float)y0;
    const float* cp = corr + (size_t)b * (S * S);
    float v0 = cp[y0 * S + x0] * (1.0f - wx) + cp[y0 * S + x1] * wx;
    float v1 = cp[y1 * S + x0] * (1.0f - wx) + cp[y1 * S + x1] * wx;
    out[((size_t)b * 3 + SCALE) * (HH * WW) + y * WW + x] = (1.0f - wy) * v0 + wy * v1;
}

extern "C" void kernel_launch(void* const* d_in, const int* in_sizes, int n_in,
                              void* d_out, int out_size, void* d_ws, size_t ws_size,
                              hipStream_t stream) {
    const float* feat1 = (const float*)d_in[0];
    const float* feat2 = (const float*)d_in[1];
    const float* offs  = (const float*)d_in[2];
    float* out = (float*)d_out;

    const size_t n_s0 = (size_t)NB * HH * WW * 64;
    const size_t n_d1 = (size_t)NB * 128 * 128 * 64;
    const size_t n_d2 = (size_t)NB * 64 * 64 * 64;
    const size_t n_c1 = (size_t)NB * 128 * 128;
    const size_t n_c2 = (size_t)NB * 64 * 64;
    const size_t need = (2 * (n_s0 + n_d1 + n_d2) + n_c1 + n_c2) * 4;
    if (ws_size < need) return;

    unsigned int* ws = (unsigned int*)d_ws;
    unsigned int* s0f1 = ws;
    unsigned int* s0f2 = s0f1 + n_s0;
    unsigned int* d1f1 = s0f2 + n_s0;
    unsigned int* d1f2 = d1f1 + n_d1;
    unsigned int* d2f1 = d1f2 + n_d1;
    unsigned int* d2f2 = d2f1 + n_d2;
    float* corr1 = (float*)(d2f2 + n_d2);
    float* corr2 = corr1 + n_c1;

    prep3_kernel<<<dim3(16, 64, 8), 256, 0, stream>>>(feat1, feat2, s0f1, s0f2,
                                                      d1f1, d1f2, d2f1, d2f2);

    corr_hwc<0><<<NB * 65536 / 16, 256, 0, stream>>>(s0f1, s0f2, offs, out);
    corr_hwc<1><<<NB * 16384 / 16, 256, 0, stream>>>(d1f1, d1f2, offs, corr1);
    corr_hwc<2><<<NB * 4096 / 16, 256, 0, stream>>>(d2f1, d2f2, offs, corr2);

    up_kernel<1><<<(NB * HH * WW + 255) / 256, 256, 0, stream>>>(corr1, out);
    up_kernel<2><<<(NB * HH * WW + 255) / 256, 256, 0, stream>>>(corr2, out);
}